// Round 7
// baseline (55.726 us; speedup 1.0000x reference)
//
#include <hip/hip_runtime.h>

#define BATCH 8
#define NCLS  19
#define LOGN  18
#define NPIX  (1u << LOGN)      // 262144 pixels per image
#define NB    64                // histogram bins over p in [0,1)
#define BLK1  512
#define CPB   32                // chunks (blocks) per image -> grid 256 = 1 block/CU
#define PPBLK (NPIX / CPB)      // 8192 px per block
#define TPX   512               // pixels per tile (1 px/thread/tile)
#define NT    (PPBLK / TPX)     // 16 tiles
#define HCOPY 8                 // LDS histogram copies (lane & 7)
#define HSTR  (NCLS * NB + 4)   // 1220 words; copies start on distinct banks

// async global->LDS, 16B per lane: LDS dest = uniform base + lane*16,
// global src = per-lane address (guide §5 / m97 / m104).
__device__ __forceinline__ void gload16(const void* g, void* l) {
    __builtin_amdgcn_global_load_lds(
        (const __attribute__((address_space(1))) unsigned*)g,
        (__attribute__((address_space(3))) unsigned*)l, 16, 0, 0);
}

// ---------------- Kernel 1: T3-style 2-phase pipeline.
// stage(t+1) -> compute(t) from LDS -> barrier (drains vmcnt). Loads for the
// next tile are in flight during the whole compute+atomic phase.
__global__ __launch_bounds__(BLK1) void k_hist(
    const float* __restrict__ pred, const int* __restrict__ target,
    unsigned short* __restrict__ hist_part, float* __restrict__ s2_part,
    unsigned short* __restrict__ cnt_part)
{
    __shared__ __align__(16) float pbuf[2][NCLS * TPX];   // 2 x 38912 B
    __shared__ __align__(16) int   tbuf[2][TPX];          // 2 x 2048 B
    __shared__ unsigned hist[HCOPY * HSTR];               // 39040 B
    __shared__ float    s2lds[NCLS];
    __shared__ unsigned cntlds[NCLS];

    const int b     = blockIdx.x / CPB;
    const int chunk = blockIdx.x % CPB;
    const int tid   = threadIdx.x;
    const int lane  = tid & 63;
    const int wid   = tid >> 6;

    unsigned* hpar = hist + (lane & (HCOPY - 1)) * HSTR;

    for (int i = tid; i < HCOPY * HSTR; i += BLK1) hist[i] = 0u;
    if (tid < NCLS) { s2lds[tid] = 0.f; cntlds[tid] = 0u; }

    const float* pb = pred + (((size_t)b * NCLS) << LOGN) + (size_t)chunk * PPBLK;
    const int*   tb = target + ((size_t)b << LOGN) + (size_t)chunk * PPBLK;

    // 40 wave-wide 1KB loads per tile (38 pred + 2 target), 5 per wave.
    auto stage = [&](int buf, int t) {
        const int px0 = t * TPX;
        #pragma unroll
        for (int j = 0; j < 5; ++j) {
            const int i = wid * 5 + j;
            if (i < 2 * NCLS) {
                const int c = i >> 1, half = i & 1;
                gload16(pb + ((size_t)c << LOGN) + px0 + half * 256 + lane * 4,
                        &pbuf[buf][c * TPX + half * 256]);
            } else if (i < 2 * NCLS + 2) {
                const int hh = i - 2 * NCLS;
                gload16(tb + px0 + hh * 256 + lane * 4, &tbuf[buf][hh * 256]);
            }
        }
    };

    stage(0, 0);
    __syncthreads();     // covers hist zero-init + drains stage(0)

    #pragma unroll 1
    for (int t = 0; t < NT; ++t) {
        const int cur = t & 1;
        if (t + 1 < NT) stage(cur ^ 1, t + 1);   // issue BEFORE compute (T3)

        // compute this thread's pixel from LDS (stride-1 ds_read, conflict-free)
        float e[NCLS];
        float s = 0.f;
        #pragma unroll
        for (int c = 0; c < NCLS; ++c) {
            e[c] = __expf(pbuf[cur][c * TPX + tid]);
            s += e[c];
        }
        const int   tg = tbuf[cur][tid];
        const float r  = __builtin_amdgcn_rcpf(s) * (float)NB;   // p*NB scale

        float et = 0.f;
        #pragma unroll
        for (int c = 0; c < NCLS; ++c) {
            const float tt = e[c] * r;
            int bin = (int)tt; bin = bin > NB - 1 ? NB - 1 : bin;
            et = (c == tg) ? e[c] : et;          // e^x of target class
            // bin 0 only contributes to S_0 = M, reconstructed exactly in k_finish
            if (c != tg && bin != 0) atomicAdd(&hpar[c * NB + bin], 1u);
        }
        atomicAdd(&s2lds[tg], fmaf(et * r, -1.0f / (float)NB, 1.0f));
        atomicAdd(&cntlds[tg], 1u);

        __syncthreads();   // buffer handoff + vmcnt drain of stage(t+1)
    }

    // transposed u16 partials: part[((b*NCLS+c)*CPB + chunk)*NB + bin]
    for (int i = tid; i < NCLS * NB; i += BLK1) {
        unsigned v = 0;
        #pragma unroll
        for (int k = 0; k < HCOPY; ++k) v += hist[k * HSTR + i];
        const int c = i >> 6, bin = i & (NB - 1);
        hist_part[((size_t)(b * NCLS + c) * CPB + chunk) * NB + bin] = (unsigned short)v;
    }
    if (tid < NCLS) {
        s2_part [(size_t)(b * NCLS + tid) * CPB + chunk] = s2lds[tid];
        cnt_part[(size_t)(b * NCLS + tid) * CPB + chunk] = (unsigned short)cntlds[tid];
    }
}

// ---------------- Kernel 2: per (b,c): sum partials, wave suffix-scan, trapezoid
// loss_bc = M/N + sum_k (dx/2)*(g(S_k)+g(S_{k+1})) + S2/N,  g(r)=r/(n_c+r),
// with S_0 := M = NPIX - n_c reconstructed exactly (bin-0 atomics were skipped).
template<int BPB>
__global__ __launch_bounds__(256) void k_finish(
    const unsigned short* __restrict__ hist_part, const float* __restrict__ s2_part,
    const unsigned short* __restrict__ cnt_part, float* __restrict__ loss_bc)
{
    __shared__ unsigned hsum[4][NB];
    __shared__ float s2tot, nctot;

    const int bc   = blockIdx.x;
    const int tid  = threadIdx.x;
    const int lane = tid & 63;
    const int w    = tid >> 6;

    const unsigned short* hp = hist_part + (size_t)bc * BPB * NB;
    unsigned h = 0;
    #pragma unroll 1
    for (int k = 0; k < BPB / 4; ++k)
        h += hp[(size_t)(w * (BPB / 4) + k) * NB + lane];
    hsum[w][lane] = h;

    if (w == 1) {
        float v = 0.f;
        for (int k = lane; k < BPB; k += 64) v += s2_part[(size_t)bc * BPB + k];
        #pragma unroll
        for (int off = 32; off > 0; off >>= 1) v += __shfl_down(v, off, 64);
        if (lane == 0) s2tot = v;
    }
    if (w == 2) {
        unsigned v = 0;
        for (int k = lane; k < BPB; k += 64) v += cnt_part[(size_t)bc * BPB + k];
        #pragma unroll
        for (int off = 32; off > 0; off >>= 1) v += __shfl_down(v, off, 64);
        if (lane == 0) nctot = (float)v;
    }
    __syncthreads();

    if (w == 0) {
        const unsigned hb = hsum[0][lane] + hsum[1][lane] + hsum[2][lane] + hsum[3][lane];
        // lane l takes bin 63-l: lane prefix-scan == bin suffix-scan
        const unsigned hrev = __shfl(hb, 63 - lane, 64);
        unsigned sc = hrev;
        #pragma unroll
        for (int off = 1; off < 64; off <<= 1) {
            const unsigned v = __shfl_up(sc, off, 64);
            if (lane >= off) sc += v;
        }
        const float ncf = nctot;
        const float Nf  = (float)NPIX;
        const float Mf  = Nf - ncf;                 // exact M
        const unsigned Rab = sc - hrev;             // S_{k+1}
        float fRh = (float)sc;                      // S_k (hist-based, lacks bin 0)
        if (lane == 63) fRh = Mf;                   // S_0 := M exactly
        const float gR  = (Rab > 0)   ? (float)Rab / ((float)Rab + ncf) : 0.0f;
        const float gRh = (fRh > 0.f) ? fRh / (fRh + ncf) : 0.0f;
        float red = gR + gRh;
        #pragma unroll
        for (int off = 32; off > 0; off >>= 1) red += __shfl_down(red, off, 64);
        if (lane == 0)
            loss_bc[bc] = Mf / Nf + red * (0.5f / (float)NB) + s2tot / Nf;
    }
}

// ---------------- Kernel 3: deterministic tree-sum of the 152 per-(b,c) losses.
__global__ __launch_bounds__(256) void k_reduce(
    const float* __restrict__ loss_bc, float* __restrict__ out)
{
    __shared__ float r[256];
    const int tid = threadIdx.x;
    r[tid] = (tid < BATCH * NCLS) ? loss_bc[tid] : 0.0f;
    __syncthreads();
    for (int off = 128; off > 0; off >>= 1) {
        if (tid < off) r[tid] += r[tid + off];
        __syncthreads();
    }
    if (tid == 0) out[0] = r[0] * (1.0f / (float)(BATCH * NCLS));
}

extern "C" void kernel_launch(void* const* d_in, const int* in_sizes, int n_in,
                              void* d_out, int out_size, void* d_ws, size_t ws_size,
                              hipStream_t stream)
{
    const float* pred   = (const float*)d_in[0];
    const int*   target = (const int*)d_in[1];
    float*       out    = (float*)d_out;
    unsigned char* ws   = (unsigned char*)d_ws;

    unsigned short* hist_part = (unsigned short*)ws;                   // 608 KB
    size_t off = (size_t)BATCH * NCLS * CPB * NB * sizeof(unsigned short);
    float* s2_part = (float*)(ws + off);
    off += (size_t)BATCH * NCLS * CPB * sizeof(float);
    unsigned short* cnt_part = (unsigned short*)(ws + off);
    off += (size_t)BATCH * NCLS * CPB * sizeof(unsigned short);
    float* loss_bc = (float*)(ws + off);

    hipLaunchKernelGGL(k_hist,        dim3(BATCH * CPB),  dim3(BLK1), 0, stream,
                       pred, target, hist_part, s2_part, cnt_part);
    hipLaunchKernelGGL(k_finish<CPB>, dim3(BATCH * NCLS), dim3(256),  0, stream,
                       hist_part, s2_part, cnt_part, loss_bc);
    hipLaunchKernelGGL(k_reduce,      dim3(1),            dim3(256),  0, stream,
                       loss_bc, out);
}